// Round 3
// 523.785 us; speedup vs baseline: 1.0678x; 1.0678x over previous
//
#include <hip/hip_runtime.h>
#include <math.h>

#define BB 32
#define LL 1024
#define EMB 512
#define DOUT 64
#define NH 8

typedef __attribute__((ext_vector_type(8))) short short8;
typedef __attribute__((ext_vector_type(4))) short short4v;
typedef __attribute__((ext_vector_type(8))) _Float16 half8;
typedef __attribute__((ext_vector_type(4))) float f32x4;

// pack 2 floats -> 2 bf16 (RNE)
__device__ __forceinline__ unsigned pk2(float a, float b) {
    unsigned ua = __float_as_uint(a);
    ua += 0x7fffu + ((ua >> 16) & 1u);
    unsigned ub = __float_as_uint(b);
    ub += 0x7fffu + ((ub >> 16) & 1u);
    return (ua >> 16) | (ub & 0xffff0000u);
}
// pack 1 float -> bf16 (RNE)
__device__ __forceinline__ unsigned short pk1(float a) {
    unsigned ua = __float_as_uint(a);
    ua += 0x7fffu + ((ua >> 16) & 1u);
    return (unsigned short)(ua >> 16);
}
__device__ __forceinline__ float bf2f(unsigned short u) {
    return __uint_as_float(((unsigned)u) << 16);
}

// async global->LDS, 16B per lane. LDS dest must be wave-uniform base; HW adds
// lane*16. Swizzled layouts are achieved by pre-swizzling the global source
// (rule #21: linear dest + inverse-swz source == swz write).
__device__ __forceinline__ void gload16(const void* g, void* l) {
    __builtin_amdgcn_global_load_lds(
        (const __attribute__((address_space(1))) void*)g,
        (__attribute__((address_space(3))) void*)l,
        16, 0, 0);
}

// Explicit drain of outstanding global_load_lds DMAs. The compiler is NOT
// guaranteed to emit s_waitcnt vmcnt(0) before s_barrier for LDS-destined
// loads (no dest register -> no dataflow dependence); round-2 post-timing
// divergence showed replays racing on undrained staging. Memory clobber
// pins subsequent ds_reads below the wait.
__device__ __forceinline__ void drain_vmcnt() {
    asm volatile("s_waitcnt vmcnt(0)" ::: "memory");
}

// ---------------------------------------------------------------------------
// Kernel 0: convert. joint -> fp16 Xh; Wq/Wk/Wv -> fp16 transposed Wth[y][n][k]
// (y = h*3+mat); Wo -> bf16 transposed Wotb[n][k].
// ---------------------------------------------------------------------------
__global__ __launch_bounds__(256) void convert_kernel(
    const float* __restrict__ joint,
    const float* __restrict__ Wq, const float* __restrict__ Wk, const float* __restrict__ Wv,
    const float* __restrict__ Wo,
    _Float16* __restrict__ Xh, _Float16* __restrict__ Wth,
    unsigned short* __restrict__ Wotb)
{
    const int blk = blockIdx.x;
    const int tid = threadIdx.x;
    if (blk < 8192) {
        const size_t idx = ((size_t)blk * 256 + tid) * 8;
        const float4 a = *reinterpret_cast<const float4*>(&joint[idx]);
        const float4 b = *reinterpret_cast<const float4*>(&joint[idx + 4]);
        half8 h;
        h[0] = (_Float16)a.x; h[1] = (_Float16)a.y; h[2] = (_Float16)a.z; h[3] = (_Float16)a.w;
        h[4] = (_Float16)b.x; h[5] = (_Float16)b.y; h[6] = (_Float16)b.z; h[7] = (_Float16)b.w;
        *reinterpret_cast<half8*>(&Xh[idx]) = h;
    } else if (blk < 8192 + 384) {
        const int gid = (blk - 8192) * 256 + tid;   // [0, 98304)
        const int y = gid >> 12;                    // [0, 24)
        const int rem = gid & 4095;
        const int n = rem >> 6;
        const int k8 = rem & 63;
        const int h = y / 3, mat = y - 3 * h;
        const float* W = (mat == 0 ? Wq : (mat == 1 ? Wk : Wv)) + (size_t)h * EMB * DOUT;
        half8 t;
        #pragma unroll
        for (int i = 0; i < 8; ++i)
            t[i] = (_Float16)W[(size_t)(k8 * 8 + i) * DOUT + n];
        *reinterpret_cast<half8*>(&Wth[(size_t)y * 32768 + n * 512 + k8 * 8]) = t;
    } else {
        const int gid = (blk - 8576) * 256 + tid;   // [0, 4096)
        const int n = gid >> 6;
        const int k8 = gid & 63;
        short4v lo, hi;
        #pragma unroll
        for (int i = 0; i < 4; ++i) lo[i] = (short)pk1(Wo[(size_t)(k8 * 8 + i) * DOUT + n]);
        #pragma unroll
        for (int i = 0; i < 4; ++i) hi[i] = (short)pk1(Wo[(size_t)(k8 * 8 + 4 + i) * DOUT + n]);
        *reinterpret_cast<short4v*>(&Wotb[(size_t)n * 512 + k8 * 8]) = lo;
        *reinterpret_cast<short4v*>(&Wotb[(size_t)n * 512 + k8 * 8 + 4]) = hi;
    }
}

// ---------------------------------------------------------------------------
// Kernel 1: QKV projection with fp16 MFMA.
// Block: 256 thr (4 waves), tile 128 rows x 64 cols, K=512 in chunks of 64.
// grid (256 rowtiles, 24 = h*3+mat). LDS tiles XOR-swizzled (16B blocks).
// Staging via global_load_lds (linear LDS dest, pre-swizzled global source),
// with EXPLICIT vmcnt(0) drain before the consume barrier.
// mfma(a,b): D[row=quad*4+r <- a's row idx][col=lane&15 <- b's row idx].
// Q/K: swapped operands -> d consecutive per lane -> natural [l][d] b64 stores.
// V: normal operands -> l consecutive per lane -> transposed [d][L] b64 stores.
// ---------------------------------------------------------------------------
template <bool VMODE>
__device__ __forceinline__ void qkv_core(
    const _Float16* __restrict__ Xh, const _Float16* __restrict__ Wy,
    _Float16* As, _Float16* Bs, f32x4 (&acc)[8], int rowbase)
{
    const int tid = threadIdx.x;
    const int lane = tid & 63;
    const int wid = tid >> 6;
    const int lq = lane & 15;
    const int quad = lane >> 4;

    for (int kb = 0; kb < EMB; kb += 64) {
        __syncthreads();
        #pragma unroll
        for (int p = 0; p < 4; ++p) {
            const int bidx = tid + p * 256;
            const int m = bidx >> 3, j = bidx & 7;
            const int jx = j ^ (m & 7);
            gload16(&Xh[(size_t)(rowbase + m) * EMB + kb + 8 * jx],
                    &As[(p * 256 + wid * 64) * 8]);
        }
        #pragma unroll
        for (int p = 0; p < 2; ++p) {
            const int bidx = tid + p * 256;
            const int n = bidx >> 3, j = bidx & 7;
            const int jx = j ^ (n & 7);
            gload16(&Wy[(size_t)n * EMB + kb + 8 * jx],
                    &Bs[(p * 256 + wid * 64) * 8]);
        }
        drain_vmcnt();
        __syncthreads();

        half8 xf[2][2], wf[4][2];
        #pragma unroll
        for (int mt = 0; mt < 2; ++mt)
            #pragma unroll
            for (int kf = 0; kf < 2; ++kf) {
                const int row = wid * 32 + mt * 16 + lq;
                xf[mt][kf] = *reinterpret_cast<const half8*>(
                    &As[row * 64 + 8 * ((4 * kf + quad) ^ (row & 7))]);
            }
        #pragma unroll
        for (int nt = 0; nt < 4; ++nt)
            #pragma unroll
            for (int kf = 0; kf < 2; ++kf)
                wf[nt][kf] = *reinterpret_cast<const half8*>(
                    &Bs[(nt * 16 + lq) * 64 + 8 * ((4 * kf + quad) ^ (lq & 7))]);

        #pragma unroll
        for (int mt = 0; mt < 2; ++mt)
            #pragma unroll
            for (int nt = 0; nt < 4; ++nt)
                #pragma unroll
                for (int kf = 0; kf < 2; ++kf) {
                    if (VMODE)
                        acc[mt * 4 + nt] = __builtin_amdgcn_mfma_f32_16x16x32_f16(
                            xf[mt][kf], wf[nt][kf], acc[mt * 4 + nt], 0, 0, 0);
                    else
                        acc[mt * 4 + nt] = __builtin_amdgcn_mfma_f32_16x16x32_f16(
                            wf[nt][kf], xf[mt][kf], acc[mt * 4 + nt], 0, 0, 0);
                }
    }
}

__global__ __launch_bounds__(256) void qkv_mfma(
    const _Float16* __restrict__ Xh, const _Float16* __restrict__ Wth,
    const float* __restrict__ bq, const float* __restrict__ bk, const float* __restrict__ bv,
    unsigned short* __restrict__ Qb, unsigned short* __restrict__ Kb,
    unsigned short* __restrict__ Vb)
{
    __shared__ __align__(16) _Float16 As[128 * 64];
    __shared__ __align__(16) _Float16 Bs[64 * 64];

    const int tid = threadIdx.x;
    const int lane = tid & 63;
    const int wid = tid >> 6;
    const int lq = lane & 15;
    const int quad = lane >> 4;

    const int rowbase = blockIdx.x * 128;
    const int y = blockIdx.y;
    const int mat = y % 3;
    const int h = y / 3;
    const _Float16* Wy = Wth + (size_t)y * 32768;
    const float* bias = (mat == 0 ? bq : (mat == 1 ? bk : bv)) + (size_t)h * DOUT;
    unsigned short* Out = (mat == 0 ? Qb : (mat == 1 ? Kb : Vb));

    f32x4 acc[8];
    #pragma unroll
    for (int i = 0; i < 8; ++i) { acc[i][0] = 0.f; acc[i][1] = 0.f; acc[i][2] = 0.f; acc[i][3] = 0.f; }

    const int b_ = rowbase >> 10;
    const int lb = rowbase & 1023;
    const size_t baseh = ((size_t)b_ * NH + h);

    if (mat == 2) {
        qkv_core<true>(Xh, Wy, As, Bs, acc, rowbase);
        // acc[mt*4+nt]: l = lb + wid*32 + mt*16 + quad*4 + r (consec), d = nt*16+lq
        #pragma unroll
        for (int nt = 0; nt < 4; ++nt) {
            const int d = nt * 16 + lq;
            const float bz = bias[d];
            #pragma unroll
            for (int mt = 0; mt < 2; ++mt) {
                short4v s;
                #pragma unroll
                for (int r = 0; r < 4; ++r) s[r] = (short)pk1(acc[mt * 4 + nt][r] + bz);
                *reinterpret_cast<short4v*>(
                    &Out[(baseh * DOUT + d) * LL + lb + wid * 32 + mt * 16 + quad * 4]) = s;
            }
        }
    } else {
        qkv_core<false>(Xh, Wy, As, Bs, acc, rowbase);
        // acc[mt*4+nt]: d = nt*16 + quad*4 + r (consec), l = lb + wid*32 + mt*16 + lq
        #pragma unroll
        for (int nt = 0; nt < 4; ++nt) {
            const float4 bz = *reinterpret_cast<const float4*>(&bias[nt * 16 + quad * 4]);
            const float bzv[4] = {bz.x, bz.y, bz.z, bz.w};
            #pragma unroll
            for (int mt = 0; mt < 2; ++mt) {
                const int l = lb + wid * 32 + mt * 16 + lq;
                short4v s;
                #pragma unroll
                for (int r = 0; r < 4; ++r) s[r] = (short)pk1(acc[mt * 4 + nt][r] + bzv[r]);
                *reinterpret_cast<short4v*>(
                    &Out[(baseh * LL + l) * DOUT + nt * 16 + quad * 4]) = s;
            }
        }
    }
}

// ---------------------------------------------------------------------------
// Kernel 2: V suffix sums. Vsuf[b][h][d] = sum_{l>=len} V[b][h][d][l].
// 256 blocks (b*h) x 256 thr; each wave owns 16 d-rows, lanes coalesce along l
// (64 lanes x 16B = 1 KiB per load), then 6-step shfl_xor wave reduction.
// ---------------------------------------------------------------------------
__global__ __launch_bounds__(256) void vsuf_kernel(
    const unsigned short* __restrict__ Vb, const int* __restrict__ traj_len,
    float* __restrict__ Vsuf)
{
    const int bh = blockIdx.x;       // [0, 256)
    const int b = bh >> 3;
    const int tid = threadIdx.x;
    const int lane = tid & 63;
    const int wid = tid >> 6;
    int len = traj_len[b];
    if (len < 0) len = 0;
    if (len > LL) len = LL;
    const int l0 = len & ~7;         // aligned start; head elems masked below

    #pragma unroll
    for (int i = 0; i < 16; ++i) {
        const int d = wid * 16 + i;
        const unsigned short* src = Vb + ((size_t)bh * DOUT + d) * LL;
        float s = 0.f;
        #pragma unroll
        for (int p = 0; p < 2; ++p) {
            const int l = l0 + p * 512 + lane * 8;
            if (l < LL) {
                const short8 v = *reinterpret_cast<const short8*>(&src[l]);
                #pragma unroll
                for (int q = 0; q < 8; ++q)
                    if (l + q >= len) s += bf2f((unsigned short)v[q]);
            }
        }
        s += __shfl_xor(s, 1);
        s += __shfl_xor(s, 2);
        s += __shfl_xor(s, 4);
        s += __shfl_xor(s, 8);
        s += __shfl_xor(s, 16);
        s += __shfl_xor(s, 32);
        if (lane == 0) Vsuf[(size_t)bh * DOUT + d] = s;
    }
}

// ---------------------------------------------------------------------------
// Kernel 3: bf16-MFMA flash attention, multiplicative mask, max-free softmax.
// Only iterates K-tiles with k < len; the k >= len region contributes p=1
// exactly (exp(0)), folded in analytically via Vsuf and (1024-len).
// Staging: register round-trip + swizzled ds_write (harness-proven baseline;
// gload_lds variant raced under graph replay in round 2).
// ---------------------------------------------------------------------------
__global__ __launch_bounds__(256, 3) void attn_kernel(
    const unsigned short* __restrict__ Qb,
    const unsigned short* __restrict__ Kb,
    const unsigned short* __restrict__ Vb,
    const float* __restrict__ Vsuf,
    const int* __restrict__ traj_len,
    unsigned short* __restrict__ Ob)
{
    __shared__ __align__(16) short lds[16384];   // 32 KB
    short* Ks = lds;              // [64 keys][64 d], swizzled
    short* Vt = lds + 4096;       // [64 d][64 keys], swizzled

    const int tid = threadIdx.x;
    const int lane = tid & 63;
    const int wid = tid >> 6;
    const int lq = lane & 15;
    const int quad = lane >> 4;
    short* Ps = lds + 8192 + wid * 2048;   // per-wave [32 q][64 k], swizzled

    const int qt = blockIdx.x;
    const int h = blockIdx.y;
    const int b = blockIdx.z;

    int len = traj_len[b];
    if (len < 0) len = 0;
    if (len > LL) len = LL;

    const size_t base = ((size_t)b * NH + h) * LL * DOUT;   // same for [l][d] and [d][L]
    const int qbase = qt * 128 + wid * 32;

    // Q fragments (bf16 direct): row = qbase+16g+lq, d = kf*32 + quad*8 .. +7
    short8 qf[2][2];
    #pragma unroll
    for (int g = 0; g < 2; ++g)
        #pragma unroll
        for (int kf = 0; kf < 2; ++kf)
            qf[g][kf] = *reinterpret_cast<const short8*>(
                &Qb[base + (size_t)(qbase + 16 * g + lq) * DOUT + kf * 32 + quad * 8]);

    const float SC = 0.04419417382415922f;   // 1/sqrt(512)
    float Mq[2];
    Mq[0] = ((qbase + lq) < len) ? SC : 0.0f;
    Mq[1] = ((qbase + 16 + lq) < len) ? SC : 0.0f;
    const int krel = len - 4 * quad;         // in-tile k valid iff kt+16nt+r < krel

    f32x4 o[2][4];
    #pragma unroll
    for (int g = 0; g < 2; ++g)
        #pragma unroll
        for (int nt = 0; nt < 4; ++nt) {
            o[g][nt][0] = 0.f; o[g][nt][1] = 0.f; o[g][nt][2] = 0.f; o[g][nt][3] = 0.f;
        }
    float l_acc[2] = {0.0f, 0.0f};

    const int kend = ((len + 63) >> 6) << 6;   // only tiles containing k < len

    for (int kt = 0; kt < kend; kt += 64) {
        __syncthreads();
        // stage K (natural rows) and V (pre-transposed rows), both coalesced b128
        #pragma unroll
        for (int p = 0; p < 2; ++p) {
            const int bidx = tid + p * 256;
            const int m = bidx >> 3, j = bidx & 7;
            const short8 tk = *reinterpret_cast<const short8*>(
                &Kb[base + (size_t)(kt + m) * DOUT + 8 * j]);
            *reinterpret_cast<short8*>(&Ks[m * 64 + 8 * (j ^ (m & 7))]) = tk;
            const short8 tv = *reinterpret_cast<const short8*>(
                &Vb[base + (size_t)m * LL + kt + 8 * j]);
            *reinterpret_cast<short8*>(&Vt[m * 64 + 8 * (j ^ (m & 7))]) = tv;
        }
        __syncthreads();

        // S^T = K . Q^T
        f32x4 sS[2][4];
        #pragma unroll
        for (int nt = 0; nt < 4; ++nt) {
            const int krow = (16 * nt + lq) * 64;
            const short8 k0 = *reinterpret_cast<const short8*>(&Ks[krow + 8 * ((0 + quad) ^ (lq & 7))]);
            const short8 k1 = *reinterpret_cast<const short8*>(&Ks[krow + 8 * ((4 + quad) ^ (lq & 7))]);
            #pragma unroll
            for (int g = 0; g < 2; ++g) {
                f32x4 z;
                z[0] = 0.f; z[1] = 0.f; z[2] = 0.f; z[3] = 0.f;
                z = __builtin_amdgcn_mfma_f32_16x16x32_bf16(k0, qf[g][0], z, 0, 0, 0);
                z = __builtin_amdgcn_mfma_f32_16x16x32_bf16(k1, qf[g][1], z, 0, 0, 0);
                sS[g][nt] = z;
            }
        }

        // p = exp(s*scale*maskq) for k<len, 0 for k>=len (suffix handles those)
        #pragma unroll
        for (int g = 0; g < 2; ++g) {
            #pragma unroll
            for (int nt = 0; nt < 4; ++nt) {
                float pv[4];
                #pragma unroll
                for (int r = 0; r < 4; ++r) {
                    const bool kv = (kt + 16 * nt + r) < krel;
                    pv[r] = kv ? __expf(sS[g][nt][r] * Mq[g]) : 0.0f;
                    l_acc[g] += pv[r];
                }
                int2 w;
                w.x = (int)pk2(pv[0], pv[1]);
                w.y = (int)pk2(pv[2], pv[3]);
                *reinterpret_cast<int2*>(
                    &Ps[(16 * g + lq) * 64 + 8 * ((2 * nt + (quad >> 1)) ^ (lq & 7)) + 4 * (quad & 1)]) = w;
            }
        }

        // O += P . V
        short8 pf[2][2];
        #pragma unroll
        for (int g = 0; g < 2; ++g)
            #pragma unroll
            for (int kf = 0; kf < 2; ++kf)
                pf[g][kf] = *reinterpret_cast<const short8*>(
                    &Ps[(16 * g + lq) * 64 + 8 * ((4 * kf + quad) ^ (lq & 7))]);

        #pragma unroll
        for (int nt = 0; nt < 4; ++nt) {
            const int vrow = (16 * nt + lq) * 64;
            const short8 v0 = *reinterpret_cast<const short8*>(&Vt[vrow + 8 * ((0 + quad) ^ (lq & 7))]);
            const short8 v1 = *reinterpret_cast<const short8*>(&Vt[vrow + 8 * ((4 + quad) ^ (lq & 7))]);
            #pragma unroll
            for (int g = 0; g < 2; ++g) {
                o[g][nt] = __builtin_amdgcn_mfma_f32_16x16x32_bf16(pf[g][0], v0, o[g][nt], 0, 0, 0);
                o[g][nt] = __builtin_amdgcn_mfma_f32_16x16x32_bf16(pf[g][1], v1, o[g][nt], 0, 0, 0);
            }
        }
    }

    // epilogue: suffix contribution + denominator, then store bf16 concat layout
    const float lext = (float)(LL - len);
    float inv[2];
    #pragma unroll
    for (int g = 0; g < 2; ++g) {
        float t = l_acc[g];
        t += __shfl_xor(t, 16);
        t += __shfl_xor(t, 32);
        inv[g] = 1.0f / (t + lext);
    }
    float iq[2][4];
    #pragma unroll
    for (int g = 0; g < 2; ++g)
        #pragma unroll
        for (int r = 0; r < 4; ++r)
            iq[g][r] = __shfl(inv[g], 4 * quad + r, 64);

    const float* vsufp = &Vsuf[((size_t)b * NH + h) * DOUT];
    #pragma unroll
    for (int g = 0; g < 2; ++g) {
        #pragma unroll
        for (int nt = 0; nt < 4; ++nt) {
            const float vs = vsufp[16 * nt + lq];
            #pragma unroll
            for (int r = 0; r < 4; ++r) {
                const int qrow = qbase + 16 * g + 4 * quad + r;
                const float val = (o[g][nt][r] + vs) * iq[g][r];
                Ob[((size_t)b * LL + qrow) * 512 + h * 64 + 16 * nt + lq] = pk1(val);
            }
        }
    }
}

// ---------------------------------------------------------------------------
// Kernel 4: output projection with bf16 MFMA. out[32768,64] = Ob[32768,512] @ Wo.
// Same structure as qkv QK-mode; fp32 float4 stores. global_load_lds staging
// with explicit vmcnt(0) drain.
// ---------------------------------------------------------------------------
__global__ __launch_bounds__(256) void outproj_mfma(
    const unsigned short* __restrict__ Ob,
    const unsigned short* __restrict__ Wotb,
    float* __restrict__ out)
{
    __shared__ __align__(16) short As[128 * 64];
    __shared__ __align__(16) short Bs[64 * 64];

    const int tid = threadIdx.x;
    const int lane = tid & 63;
    const int wid = tid >> 6;
    const int lq = lane & 15;
    const int quad = lane >> 4;
    const int rowbase = blockIdx.x * 128;

    f32x4 acc[8];
    #pragma unroll
    for (int i = 0; i < 8; ++i) { acc[i][0] = 0.f; acc[i][1] = 0.f; acc[i][2] = 0.f; acc[i][3] = 0.f; }

    for (int kb = 0; kb < 512; kb += 64) {
        __syncthreads();
        #pragma unroll
        for (int p = 0; p < 4; ++p) {
            const int bidx = tid + p * 256;
            const int m = bidx >> 3, j = bidx & 7;
            const int jx = j ^ (m & 7);
            gload16(&Ob[(size_t)(rowbase + m) * 512 + kb + 8 * jx],
                    &As[(p * 256 + wid * 64) * 8]);
        }
        #pragma unroll
        for (int p = 0; p < 2; ++p) {
            const int bidx = tid + p * 256;
            const int n = bidx >> 3, j = bidx & 7;
            const int jx = j ^ (n & 7);
            gload16(&Wotb[(size_t)n * 512 + kb + 8 * jx],
                    &Bs[(p * 256 + wid * 64) * 8]);
        }
        drain_vmcnt();
        __syncthreads();

        short8 xf[2][2], wf[4][2];
        #pragma unroll
        for (int mt = 0; mt < 2; ++mt)
            #pragma unroll
            for (int kf = 0; kf < 2; ++kf) {
                const int row = wid * 32 + mt * 16 + lq;
                xf[mt][kf] = *reinterpret_cast<const short8*>(
                    &As[row * 64 + 8 * ((4 * kf + quad) ^ (row & 7))]);
            }
        #pragma unroll
        for (int nt = 0; nt < 4; ++nt)
            #pragma unroll
            for (int kf = 0; kf < 2; ++kf)
                wf[nt][kf] = *reinterpret_cast<const short8*>(
                    &Bs[(nt * 16 + lq) * 64 + 8 * ((4 * kf + quad) ^ (lq & 7))]);

        #pragma unroll
        for (int mt = 0; mt < 2; ++mt)
            #pragma unroll
            for (int nt = 0; nt < 4; ++nt)
                #pragma unroll
                for (int kf = 0; kf < 2; ++kf)
                    acc[mt * 4 + nt] = __builtin_amdgcn_mfma_f32_16x16x32_bf16(
                        wf[nt][kf], xf[mt][kf], acc[mt * 4 + nt], 0, 0, 0);
    }

    // acc[mt*4+nt]: d = nt*16 + quad*4 + r (consec), row = rowbase + wid*32 + mt*16 + lq
    #pragma unroll
    for (int nt = 0; nt < 4; ++nt)
        #pragma unroll
        for (int mt = 0; mt < 2; ++mt) {
            const int row = rowbase + wid * 32 + mt * 16 + lq;
            float4 ov;
            ov.x = acc[mt * 4 + nt][0];
            ov.y = acc[mt * 4 + nt][1];
            ov.z = acc[mt * 4 + nt][2];
            ov.w = acc[mt * 4 + nt][3];
            *reinterpret_cast<float4*>(&out[(size_t)row * DOUT + nt * 16 + quad * 4]) = ov;
        }
}

// ---------------------------------------------------------------------------
extern "C" void kernel_launch(void* const* d_in, const int* in_sizes, int n_in,
                              void* d_out, int out_size, void* d_ws, size_t ws_size,
                              hipStream_t stream) {
    const float* joint = (const float*)d_in[0];
    // d_in[1] = delta: dead input (only defines mask shape); never read.
    const int* traj = (const int*)d_in[2];
    const float* Wq = (const float*)d_in[3];
    const float* Wk = (const float*)d_in[4];
    const float* Wv = (const float*)d_in[5];
    const float* bq = (const float*)d_in[6];
    const float* bk = (const float*)d_in[7];
    const float* bv = (const float*)d_in[8];
    const float* Wo = (const float*)d_in[9];
    float* out = (float*)d_out;

    char* ws = (char*)d_ws;
    _Float16* Xh          = (_Float16*)(ws);                    // 33,554,432 B
    _Float16* Wth         = (_Float16*)(ws + 33554432);         //  1,572,864 B
    unsigned short* Wotb  = (unsigned short*)(ws + 35127296);   //     65,536 B
    unsigned short* Qb    = (unsigned short*)(ws + 35192832);   // 33,554,432 B
    unsigned short* Kb    = (unsigned short*)(ws + 68747264);   // 33,554,432 B
    unsigned short* Vb    = (unsigned short*)(ws + 102301696);  // 33,554,432 B
    unsigned short* Ob    = (unsigned short*)(ws + 135856128);  // 33,554,432 B
    float* Vsuf           = (float*)(ws + 169410560);           //     65,536 B

    convert_kernel<<<8592, 256, 0, stream>>>(joint, Wq, Wk, Wv, Wo, Xh, Wth, Wotb);
    qkv_mfma<<<dim3(256, 24), 256, 0, stream>>>(Xh, Wth, bq, bk, bv, Qb, Kb, Vb);
    vsuf_kernel<<<256, 256, 0, stream>>>(Vb, traj, Vsuf);
    attn_kernel<<<dim3(8, NH, BB), 256, 0, stream>>>(Qb, Kb, Vb, Vsuf, traj, Ob);
    outproj_mfma<<<256, 256, 0, stream>>>(Ob, Wotb, out);
}

// Round 4
// 519.409 us; speedup vs baseline: 1.0768x; 1.0084x over previous
//
#include <hip/hip_runtime.h>
#include <math.h>

#define BB 32
#define LL 1024
#define EMB 512
#define DOUT 64
#define NH 8

typedef __attribute__((ext_vector_type(8))) short short8;
typedef __attribute__((ext_vector_type(4))) short short4v;
typedef __attribute__((ext_vector_type(8))) _Float16 half8;
typedef __attribute__((ext_vector_type(4))) float f32x4;

// pack 2 floats -> 2 bf16 (RNE)
__device__ __forceinline__ unsigned pk2(float a, float b) {
    unsigned ua = __float_as_uint(a);
    ua += 0x7fffu + ((ua >> 16) & 1u);
    unsigned ub = __float_as_uint(b);
    ub += 0x7fffu + ((ub >> 16) & 1u);
    return (ua >> 16) | (ub & 0xffff0000u);
}
// pack 1 float -> bf16 (RNE)
__device__ __forceinline__ unsigned short pk1(float a) {
    unsigned ua = __float_as_uint(a);
    ua += 0x7fffu + ((ua >> 16) & 1u);
    return (unsigned short)(ua >> 16);
}
__device__ __forceinline__ float bf2f(unsigned short u) {
    return __uint_as_float(((unsigned)u) << 16);
}

// async global->LDS, 16B per lane. LDS dest must be wave-uniform base; HW adds
// lane*16. Swizzled layouts are achieved by pre-swizzling the global source
// (rule #21: linear dest + inverse-swz source == swz write).
__device__ __forceinline__ void gload16(const void* g, void* l) {
    __builtin_amdgcn_global_load_lds(
        (const __attribute__((address_space(1))) void*)g,
        (__attribute__((address_space(3))) void*)l,
        16, 0, 0);
}

// Explicit drain of outstanding global_load_lds DMAs. hipcc is NOT guaranteed
// to emit s_waitcnt vmcnt(0) before s_barrier for LDS-destined loads (no dest
// register -> no dataflow dependence); round-2 post-timing divergence showed
// replays racing on undrained staging. Memory clobber pins ds_reads below.
__device__ __forceinline__ void drain_vmcnt() {
    asm volatile("s_waitcnt vmcnt(0)" ::: "memory");
}

// ---------------------------------------------------------------------------
// Kernel 0: convert. joint -> fp16 Xh; Wq/Wk/Wv -> fp16 transposed Wth[y][n][k]
// (y = h*3+mat); Wo -> bf16 transposed Wotb[n][k].
// ---------------------------------------------------------------------------
__global__ __launch_bounds__(256) void convert_kernel(
    const float* __restrict__ joint,
    const float* __restrict__ Wq, const float* __restrict__ Wk, const float* __restrict__ Wv,
    const float* __restrict__ Wo,
    _Float16* __restrict__ Xh, _Float16* __restrict__ Wth,
    unsigned short* __restrict__ Wotb)
{
    const int blk = blockIdx.x;
    const int tid = threadIdx.x;
    if (blk < 8192) {
        const size_t idx = ((size_t)blk * 256 + tid) * 8;
        const float4 a = *reinterpret_cast<const float4*>(&joint[idx]);
        const float4 b = *reinterpret_cast<const float4*>(&joint[idx + 4]);
        half8 h;
        h[0] = (_Float16)a.x; h[1] = (_Float16)a.y; h[2] = (_Float16)a.z; h[3] = (_Float16)a.w;
        h[4] = (_Float16)b.x; h[5] = (_Float16)b.y; h[6] = (_Float16)b.z; h[7] = (_Float16)b.w;
        *reinterpret_cast<half8*>(&Xh[idx]) = h;
    } else if (blk < 8192 + 384) {
        const int gid = (blk - 8192) * 256 + tid;   // [0, 98304)
        const int y = gid >> 12;                    // [0, 24)
        const int rem = gid & 4095;
        const int n = rem >> 6;
        const int k8 = rem & 63;
        const int h = y / 3, mat = y - 3 * h;
        const float* W = (mat == 0 ? Wq : (mat == 1 ? Wk : Wv)) + (size_t)h * EMB * DOUT;
        half8 t;
        #pragma unroll
        for (int i = 0; i < 8; ++i)
            t[i] = (_Float16)W[(size_t)(k8 * 8 + i) * DOUT + n];
        *reinterpret_cast<half8*>(&Wth[(size_t)y * 32768 + n * 512 + k8 * 8]) = t;
    } else {
        const int gid = (blk - 8576) * 256 + tid;   // [0, 4096)
        const int n = gid >> 6;
        const int k8 = gid & 63;
        short4v lo, hi;
        #pragma unroll
        for (int i = 0; i < 4; ++i) lo[i] = (short)pk1(Wo[(size_t)(k8 * 8 + i) * DOUT + n]);
        #pragma unroll
        for (int i = 0; i < 4; ++i) hi[i] = (short)pk1(Wo[(size_t)(k8 * 8 + 4 + i) * DOUT + n]);
        *reinterpret_cast<short4v*>(&Wotb[(size_t)n * 512 + k8 * 8]) = lo;
        *reinterpret_cast<short4v*>(&Wotb[(size_t)n * 512 + k8 * 8 + 4]) = hi;
    }
}

// ---------------------------------------------------------------------------
// Kernel 1: QKV projection with fp16 MFMA.
// Block: 256 thr (4 waves), tile 128 rows x 64 cols, K=512 in chunks of 64.
// grid (256 rowtiles, 24 = h*3+mat). LDS tiles XOR-swizzled (16B blocks).
// Staging via global_load_lds (linear LDS dest, pre-swizzled global source),
// with EXPLICIT vmcnt(0) drain before the consume barrier.
// mfma(a,b): D[row=quad*4+r <- a's row idx][col=lane&15 <- b's row idx].
// Q/K: swapped operands -> d consecutive per lane -> natural [l][d] b64 stores.
// V: normal operands -> l consecutive per lane -> transposed [d][L] b64 stores.
// ---------------------------------------------------------------------------
template <bool VMODE>
__device__ __forceinline__ void qkv_core(
    const _Float16* __restrict__ Xh, const _Float16* __restrict__ Wy,
    _Float16* As, _Float16* Bs, f32x4 (&acc)[8], int rowbase)
{
    const int tid = threadIdx.x;
    const int lane = tid & 63;
    const int wid = tid >> 6;
    const int lq = lane & 15;
    const int quad = lane >> 4;

    for (int kb = 0; kb < EMB; kb += 64) {
        __syncthreads();
        #pragma unroll
        for (int p = 0; p < 4; ++p) {
            const int bidx = tid + p * 256;
            const int m = bidx >> 3, j = bidx & 7;
            const int jx = j ^ (m & 7);
            gload16(&Xh[(size_t)(rowbase + m) * EMB + kb + 8 * jx],
                    &As[(p * 256 + wid * 64) * 8]);
        }
        #pragma unroll
        for (int p = 0; p < 2; ++p) {
            const int bidx = tid + p * 256;
            const int n = bidx >> 3, j = bidx & 7;
            const int jx = j ^ (n & 7);
            gload16(&Wy[(size_t)n * EMB + kb + 8 * jx],
                    &Bs[(p * 256 + wid * 64) * 8]);
        }
        drain_vmcnt();
        __syncthreads();

        half8 xf[2][2], wf[4][2];
        #pragma unroll
        for (int mt = 0; mt < 2; ++mt)
            #pragma unroll
            for (int kf = 0; kf < 2; ++kf) {
                const int row = wid * 32 + mt * 16 + lq;
                xf[mt][kf] = *reinterpret_cast<const half8*>(
                    &As[row * 64 + 8 * ((4 * kf + quad) ^ (row & 7))]);
            }
        #pragma unroll
        for (int nt = 0; nt < 4; ++nt)
            #pragma unroll
            for (int kf = 0; kf < 2; ++kf)
                wf[nt][kf] = *reinterpret_cast<const half8*>(
                    &Bs[(nt * 16 + lq) * 64 + 8 * ((4 * kf + quad) ^ (lq & 7))]);

        #pragma unroll
        for (int mt = 0; mt < 2; ++mt)
            #pragma unroll
            for (int nt = 0; nt < 4; ++nt)
                #pragma unroll
                for (int kf = 0; kf < 2; ++kf) {
                    if (VMODE)
                        acc[mt * 4 + nt] = __builtin_amdgcn_mfma_f32_16x16x32_f16(
                            xf[mt][kf], wf[nt][kf], acc[mt * 4 + nt], 0, 0, 0);
                    else
                        acc[mt * 4 + nt] = __builtin_amdgcn_mfma_f32_16x16x32_f16(
                            wf[nt][kf], xf[mt][kf], acc[mt * 4 + nt], 0, 0, 0);
                }
    }
}

__global__ __launch_bounds__(256) void qkv_mfma(
    const _Float16* __restrict__ Xh, const _Float16* __restrict__ Wth,
    const float* __restrict__ bq, const float* __restrict__ bk, const float* __restrict__ bv,
    unsigned short* __restrict__ Qb, unsigned short* __restrict__ Kb,
    unsigned short* __restrict__ Vb)
{
    __shared__ __align__(16) _Float16 As[128 * 64];
    __shared__ __align__(16) _Float16 Bs[64 * 64];

    const int tid = threadIdx.x;
    const int lane = tid & 63;
    const int wid = tid >> 6;
    const int lq = lane & 15;
    const int quad = lane >> 4;

    const int rowbase = blockIdx.x * 128;
    const int y = blockIdx.y;
    const int mat = y % 3;
    const int h = y / 3;
    const _Float16* Wy = Wth + (size_t)y * 32768;
    const float* bias = (mat == 0 ? bq : (mat == 1 ? bk : bv)) + (size_t)h * DOUT;
    unsigned short* Out = (mat == 0 ? Qb : (mat == 1 ? Kb : Vb));

    f32x4 acc[8];
    #pragma unroll
    for (int i = 0; i < 8; ++i) { acc[i][0] = 0.f; acc[i][1] = 0.f; acc[i][2] = 0.f; acc[i][3] = 0.f; }

    const int b_ = rowbase >> 10;
    const int lb = rowbase & 1023;
    const size_t baseh = ((size_t)b_ * NH + h);

    if (mat == 2) {
        qkv_core<true>(Xh, Wy, As, Bs, acc, rowbase);
        // acc[mt*4+nt]: l = lb + wid*32 + mt*16 + quad*4 + r (consec), d = nt*16+lq
        #pragma unroll
        for (int nt = 0; nt < 4; ++nt) {
            const int d = nt * 16 + lq;
            const float bz = bias[d];
            #pragma unroll
            for (int mt = 0; mt < 2; ++mt) {
                short4v s;
                #pragma unroll
                for (int r = 0; r < 4; ++r) s[r] = (short)pk1(acc[mt * 4 + nt][r] + bz);
                *reinterpret_cast<short4v*>(
                    &Out[(baseh * DOUT + d) * LL + lb + wid * 32 + mt * 16 + quad * 4]) = s;
            }
        }
    } else {
        qkv_core<false>(Xh, Wy, As, Bs, acc, rowbase);
        // acc[mt*4+nt]: d = nt*16 + quad*4 + r (consec), l = lb + wid*32 + mt*16 + lq
        #pragma unroll
        for (int nt = 0; nt < 4; ++nt) {
            const float4 bz = *reinterpret_cast<const float4*>(&bias[nt * 16 + quad * 4]);
            const float bzv[4] = {bz.x, bz.y, bz.z, bz.w};
            #pragma unroll
            for (int mt = 0; mt < 2; ++mt) {
                const int l = lb + wid * 32 + mt * 16 + lq;
                short4v s;
                #pragma unroll
                for (int r = 0; r < 4; ++r) s[r] = (short)pk1(acc[mt * 4 + nt][r] + bzv[r]);
                *reinterpret_cast<short4v*>(
                    &Out[(baseh * LL + l) * DOUT + nt * 16 + quad * 4]) = s;
            }
        }
    }
}

// ---------------------------------------------------------------------------
// Kernel 2: V sums. Vsuf[bh][d] = sum_{l>=len} V[bh][d][l];
//                  Vtot[bh][d] = sum over ALL l (for the attn fast path).
// 256 blocks (b*h) x 256 thr; each wave owns 16 d-rows, lanes coalesce along l
// (64 lanes x 16B = 1 KiB per load), then 6-step shfl_xor wave reduction.
// ---------------------------------------------------------------------------
__global__ __launch_bounds__(256) void vsuf_kernel(
    const unsigned short* __restrict__ Vb, const int* __restrict__ traj_len,
    float* __restrict__ Vsuf, float* __restrict__ Vtot)
{
    const int bh = blockIdx.x;       // [0, 256)
    const int b = bh >> 3;
    const int tid = threadIdx.x;
    const int lane = tid & 63;
    const int wid = tid >> 6;
    int len = traj_len[b];
    if (len < 0) len = 0;
    if (len > LL) len = LL;

    #pragma unroll
    for (int i = 0; i < 16; ++i) {
        const int d = wid * 16 + i;
        const unsigned short* src = Vb + ((size_t)bh * DOUT + d) * LL;
        float stot = 0.f, ssuf = 0.f;
        #pragma unroll
        for (int p = 0; p < 2; ++p) {
            const int l = p * 512 + lane * 8;
            const short8 v = *reinterpret_cast<const short8*>(&src[l]);
            #pragma unroll
            for (int q = 0; q < 8; ++q) {
                const float f = bf2f((unsigned short)v[q]);
                stot += f;
                if (l + q >= len) ssuf += f;
            }
        }
        #pragma unroll
        for (int sh = 1; sh < 64; sh <<= 1) {
            ssuf += __shfl_xor(ssuf, sh);
            stot += __shfl_xor(stot, sh);
        }
        if (lane == 0) {
            Vsuf[(size_t)bh * DOUT + d] = ssuf;
            Vtot[(size_t)bh * DOUT + d] = stot;
        }
    }
}

// ---------------------------------------------------------------------------
// Kernel 3: bf16-MFMA flash attention, multiplicative mask, max-free softmax.
// Only iterates K-tiles with k < len; the k >= len region contributes p=1
// exactly (exp(0)), folded in analytically via Vsuf and (1024-len).
// FAST PATH: blocks whose 128 q-rows are all >= len have all-zero mask rows ->
// softmax uniform over all 1024 keys -> out = Vtot/1024. Skips the K-loop
// entirely (~37% of expected K-loop work for len ~ U[0,1024)).
// Staging: register round-trip + swizzled ds_write (harness-proven).
// ---------------------------------------------------------------------------
__global__ __launch_bounds__(256, 3) void attn_kernel(
    const unsigned short* __restrict__ Qb,
    const unsigned short* __restrict__ Kb,
    const unsigned short* __restrict__ Vb,
    const float* __restrict__ Vsuf,
    const float* __restrict__ Vtot,
    const int* __restrict__ traj_len,
    unsigned short* __restrict__ Ob)
{
    __shared__ __align__(16) short lds[16384];   // 32 KB
    short* Ks = lds;              // [64 keys][64 d], swizzled
    short* Vt = lds + 4096;       // [64 d][64 keys], swizzled

    const int tid = threadIdx.x;
    const int lane = tid & 63;
    const int wid = tid >> 6;
    const int lq = lane & 15;
    const int quad = lane >> 4;
    short* Ps = lds + 8192 + wid * 2048;   // per-wave [32 q][64 k], swizzled

    const int qt = blockIdx.x;
    const int h = blockIdx.y;
    const int b = blockIdx.z;

    int len = traj_len[b];
    if (len < 0) len = 0;
    if (len > LL) len = LL;

    // ---- fast path: whole block's q rows invalid -> out = Vtot/1024 ----
    if (qt * 128 >= len) {
        const float* vt = &Vtot[((size_t)b * NH + h) * DOUT];
        const int j = tid & 7;             // column octet
        short8 s;
        #pragma unroll
        for (int q = 0; q < 8; ++q)
            s[q] = (short)pk1(vt[j * 8 + q] * 0.0009765625f);   // exact 2^-10
        #pragma unroll
        for (int pass = 0; pass < 4; ++pass) {
            const int row = qt * 128 + (tid >> 3) + pass * 32;
            *reinterpret_cast<short8*>(
                &Ob[((size_t)b * LL + row) * 512 + h * 64 + j * 8]) = s;
        }
        return;
    }

    const size_t base = ((size_t)b * NH + h) * LL * DOUT;   // same for [l][d] and [d][L]
    const int qbase = qt * 128 + wid * 32;

    // Q fragments (bf16 direct): row = qbase+16g+lq, d = kf*32 + quad*8 .. +7
    short8 qf[2][2];
    #pragma unroll
    for (int g = 0; g < 2; ++g)
        #pragma unroll
        for (int kf = 0; kf < 2; ++kf)
            qf[g][kf] = *reinterpret_cast<const short8*>(
                &Qb[base + (size_t)(qbase + 16 * g + lq) * DOUT + kf * 32 + quad * 8]);

    const float SC = 0.04419417382415922f;   // 1/sqrt(512)
    float Mq[2];
    Mq[0] = ((qbase + lq) < len) ? SC : 0.0f;
    Mq[1] = ((qbase + 16 + lq) < len) ? SC : 0.0f;
    const int krel = len - 4 * quad;         // in-tile k valid iff kt+16nt+r < krel

    f32x4 o[2][4];
    #pragma unroll
    for (int g = 0; g < 2; ++g)
        #pragma unroll
        for (int nt = 0; nt < 4; ++nt) {
            o[g][nt][0] = 0.f; o[g][nt][1] = 0.f; o[g][nt][2] = 0.f; o[g][nt][3] = 0.f;
        }
    float l_acc[2] = {0.0f, 0.0f};

    const int kend = ((len + 63) >> 6) << 6;   // only tiles containing k < len

    for (int kt = 0; kt < kend; kt += 64) {
        __syncthreads();
        // stage K (natural rows) and V (pre-transposed rows), both coalesced b128
        #pragma unroll
        for (int p = 0; p < 2; ++p) {
            const int bidx = tid + p * 256;
            const int m = bidx >> 3, j = bidx & 7;
            const short8 tk = *reinterpret_cast<const short8*>(
                &Kb[base + (size_t)(kt + m) * DOUT + 8 * j]);
            *reinterpret_cast<short8*>(&Ks[m * 64 + 8 * (j ^ (m & 7))]) = tk;
            const short8 tv = *reinterpret_cast<const short8*>(
                &Vb[base + (size_t)m * LL + kt + 8 * j]);
            *reinterpret_cast<short8*>(&Vt[m * 64 + 8 * (j ^ (m & 7))]) = tv;
        }
        __syncthreads();

        // S^T = K . Q^T
        f32x4 sS[2][4];
        #pragma unroll
        for (int nt = 0; nt < 4; ++nt) {
            const int krow = (16 * nt + lq) * 64;
            const short8 k0 = *reinterpret_cast<const short8*>(&Ks[krow + 8 * ((0 + quad) ^ (lq & 7))]);
            const short8 k1 = *reinterpret_cast<const short8*>(&Ks[krow + 8 * ((4 + quad) ^ (lq & 7))]);
            #pragma unroll
            for (int g = 0; g < 2; ++g) {
                f32x4 z;
                z[0] = 0.f; z[1] = 0.f; z[2] = 0.f; z[3] = 0.f;
                z = __builtin_amdgcn_mfma_f32_16x16x32_bf16(k0, qf[g][0], z, 0, 0, 0);
                z = __builtin_amdgcn_mfma_f32_16x16x32_bf16(k1, qf[g][1], z, 0, 0, 0);
                sS[g][nt] = z;
            }
        }

        // p = exp(s*scale*maskq) for k<len, 0 for k>=len (suffix handles those)
        #pragma unroll
        for (int g = 0; g < 2; ++g) {
            #pragma unroll
            for (int nt = 0; nt < 4; ++nt) {
                float pv[4];
                #pragma unroll
                for (int r = 0; r < 4; ++r) {
                    const bool kv = (kt + 16 * nt + r) < krel;
                    pv[r] = kv ? __expf(sS[g][nt][r] * Mq[g]) : 0.0f;
                    l_acc[g] += pv[r];
                }
                int2 w;
                w.x = (int)pk2(pv[0], pv[1]);
                w.y = (int)pk2(pv[2], pv[3]);
                *reinterpret_cast<int2*>(
                    &Ps[(16 * g + lq) * 64 + 8 * ((2 * nt + (quad >> 1)) ^ (lq & 7)) + 4 * (quad & 1)]) = w;
            }
        }

        // O += P . V
        short8 pf[2][2];
        #pragma unroll
        for (int g = 0; g < 2; ++g)
            #pragma unroll
            for (int kf = 0; kf < 2; ++kf)
                pf[g][kf] = *reinterpret_cast<const short8*>(
                    &Ps[(16 * g + lq) * 64 + 8 * ((4 * kf + quad) ^ (lq & 7))]);

        #pragma unroll
        for (int nt = 0; nt < 4; ++nt) {
            const int vrow = (16 * nt + lq) * 64;
            const short8 v0 = *reinterpret_cast<const short8*>(&Vt[vrow + 8 * ((0 + quad) ^ (lq & 7))]);
            const short8 v1 = *reinterpret_cast<const short8*>(&Vt[vrow + 8 * ((4 + quad) ^ (lq & 7))]);
            #pragma unroll
            for (int g = 0; g < 2; ++g) {
                o[g][nt] = __builtin_amdgcn_mfma_f32_16x16x32_bf16(pf[g][0], v0, o[g][nt], 0, 0, 0);
                o[g][nt] = __builtin_amdgcn_mfma_f32_16x16x32_bf16(pf[g][1], v1, o[g][nt], 0, 0, 0);
            }
        }
    }

    // epilogue: suffix contribution + denominator, then store bf16 concat layout
    const float lext = (float)(LL - len);
    float inv[2];
    #pragma unroll
    for (int g = 0; g < 2; ++g) {
        float t = l_acc[g];
        t += __shfl_xor(t, 16);
        t += __shfl_xor(t, 32);
        inv[g] = 1.0f / (t + lext);
    }
    float iq[2][4];
    #pragma unroll
    for (int g = 0; g < 2; ++g)
        #pragma unroll
        for (int r = 0; r < 4; ++r)
            iq[g][r] = __shfl(inv[g], 4 * quad + r, 64);

    const float* vsufp = &Vsuf[((size_t)b * NH + h) * DOUT];
    #pragma unroll
    for (int g = 0; g < 2; ++g) {
        #pragma unroll
        for (int nt = 0; nt < 4; ++nt) {
            const float vs = vsufp[16 * nt + lq];
            #pragma unroll
            for (int r = 0; r < 4; ++r) {
                const int qrow = qbase + 16 * g + 4 * quad + r;
                const float val = (o[g][nt][r] + vs) * iq[g][r];
                Ob[((size_t)b * LL + qrow) * 512 + h * 64 + 16 * nt + lq] = pk1(val);
            }
        }
    }
}

// ---------------------------------------------------------------------------
// Kernel 4: output projection with bf16 MFMA. out[32768,64] = Ob[32768,512] @ Wo.
// Same structure as qkv QK-mode; fp32 float4 stores. global_load_lds staging
// with explicit vmcnt(0) drain.
// ---------------------------------------------------------------------------
__global__ __launch_bounds__(256) void outproj_mfma(
    const unsigned short* __restrict__ Ob,
    const unsigned short* __restrict__ Wotb,
    float* __restrict__ out)
{
    __shared__ __align__(16) short As[128 * 64];
    __shared__ __align__(16) short Bs[64 * 64];

    const int tid = threadIdx.x;
    const int lane = tid & 63;
    const int wid = tid >> 6;
    const int lq = lane & 15;
    const int quad = lane >> 4;
    const int rowbase = blockIdx.x * 128;

    f32x4 acc[8];
    #pragma unroll
    for (int i = 0; i < 8; ++i) { acc[i][0] = 0.f; acc[i][1] = 0.f; acc[i][2] = 0.f; acc[i][3] = 0.f; }

    for (int kb = 0; kb < 512; kb += 64) {
        __syncthreads();
        #pragma unroll
        for (int p = 0; p < 4; ++p) {
            const int bidx = tid + p * 256;
            const int m = bidx >> 3, j = bidx & 7;
            const int jx = j ^ (m & 7);
            gload16(&Ob[(size_t)(rowbase + m) * 512 + kb + 8 * jx],
                    &As[(p * 256 + wid * 64) * 8]);
        }
        #pragma unroll
        for (int p = 0; p < 2; ++p) {
            const int bidx = tid + p * 256;
            const int n = bidx >> 3, j = bidx & 7;
            const int jx = j ^ (n & 7);
            gload16(&Wotb[(size_t)n * 512 + kb + 8 * jx],
                    &Bs[(p * 256 + wid * 64) * 8]);
        }
        drain_vmcnt();
        __syncthreads();

        short8 xf[2][2], wf[4][2];
        #pragma unroll
        for (int mt = 0; mt < 2; ++mt)
            #pragma unroll
            for (int kf = 0; kf < 2; ++kf) {
                const int row = wid * 32 + mt * 16 + lq;
                xf[mt][kf] = *reinterpret_cast<const short8*>(
                    &As[row * 64 + 8 * ((4 * kf + quad) ^ (row & 7))]);
            }
        #pragma unroll
        for (int nt = 0; nt < 4; ++nt)
            #pragma unroll
            for (int kf = 0; kf < 2; ++kf)
                wf[nt][kf] = *reinterpret_cast<const short8*>(
                    &Bs[(nt * 16 + lq) * 64 + 8 * ((4 * kf + quad) ^ (lq & 7))]);

        #pragma unroll
        for (int mt = 0; mt < 2; ++mt)
            #pragma unroll
            for (int nt = 0; nt < 4; ++nt)
                #pragma unroll
                for (int kf = 0; kf < 2; ++kf)
                    acc[mt * 4 + nt] = __builtin_amdgcn_mfma_f32_16x16x32_bf16(
                        wf[nt][kf], xf[mt][kf], acc[mt * 4 + nt], 0, 0, 0);
    }

    // acc[mt*4+nt]: d = nt*16 + quad*4 + r (consec), row = rowbase + wid*32 + mt*16 + lq
    #pragma unroll
    for (int nt = 0; nt < 4; ++nt)
        #pragma unroll
        for (int mt = 0; mt < 2; ++mt) {
            const int row = rowbase + wid * 32 + mt * 16 + lq;
            float4 ov;
            ov.x = acc[mt * 4 + nt][0];
            ov.y = acc[mt * 4 + nt][1];
            ov.z = acc[mt * 4 + nt][2];
            ov.w = acc[mt * 4 + nt][3];
            *reinterpret_cast<float4*>(&out[(size_t)row * DOUT + nt * 16 + quad * 4]) = ov;
        }
}

// ---------------------------------------------------------------------------
extern "C" void kernel_launch(void* const* d_in, const int* in_sizes, int n_in,
                              void* d_out, int out_size, void* d_ws, size_t ws_size,
                              hipStream_t stream) {
    const float* joint = (const float*)d_in[0];
    // d_in[1] = delta: dead input (only defines mask shape); never read.
    const int* traj = (const int*)d_in[2];
    const float* Wq = (const float*)d_in[3];
    const float* Wk = (const float*)d_in[4];
    const float* Wv = (const float*)d_in[5];
    const float* bq = (const float*)d_in[6];
    const float* bk = (const float*)d_in[7];
    const float* bv = (const float*)d_in[8];
    const float* Wo = (const float*)d_in[9];
    float* out = (float*)d_out;

    char* ws = (char*)d_ws;
    _Float16* Xh          = (_Float16*)(ws);                    // 33,554,432 B
    _Float16* Wth         = (_Float16*)(ws + 33554432);         //  1,572,864 B
    unsigned short* Wotb  = (unsigned short*)(ws + 35127296);   //     65,536 B
    unsigned short* Qb    = (unsigned short*)(ws + 35192832);   // 33,554,432 B
    unsigned short* Kb    = (unsigned short*)(ws + 68747264);   // 33,554,432 B
    unsigned short* Vb    = (unsigned short*)(ws + 102301696);  // 33,554,432 B
    unsigned short* Ob    = (unsigned short*)(ws + 135856128);  // 33,554,432 B
    float* Vsuf           = (float*)(ws + 169410560);           //     65,536 B
    // Vtot aliases the Xh region: Xh is dead after qkv_mfma, and convert
    // rewrites it at the start of every replay -> replay-deterministic.
    float* Vtot           = (float*)(ws);                       //     65,536 B

    convert_kernel<<<8592, 256, 0, stream>>>(joint, Wq, Wk, Wv, Wo, Xh, Wth, Wotb);
    qkv_mfma<<<dim3(256, 24), 256, 0, stream>>>(Xh, Wth, bq, bk, bv, Qb, Kb, Vb);
    vsuf_kernel<<<256, 256, 0, stream>>>(Vb, traj, Vsuf, Vtot);
    attn_kernel<<<dim3(8, NH, BB), 256, 0, stream>>>(Qb, Kb, Vb, Vsuf, Vtot, traj, Ob);
    outproj_mfma<<<256, 256, 0, stream>>>(Ob, Wotb, out);
}